// Round 6
// baseline (116.326 us; speedup 1.0000x reference)
//
#include <hip/hip_runtime.h>

#define COORD 5.0f
#define NO_OBJ 0.5f
#define NCELLS (8192 * 49)
#define INV_B (1.0f / 8192.0f)

#define CPB 128                      // threads per block = cells per tile
#define FPT (CPB * 30)               // floats per tile per array = 3840 (15360 B)
#define NTILES (NCELLS / CPB)        // 3136 tiles
#define NPBLK 512                    // persistent blocks: 2/CU, each does 6-7 tiles

__device__ __forceinline__ float iou_calc(float ax1, float ay1, float ax2, float ay2,
                                          float bx1, float by1, float bx2, float by2) {
    float iw = fminf(ax2, bx2) - fmaxf(ax1, bx1);
    iw = fmaxf(iw, 0.0f);
    float ih = fminf(ay2, by2) - fmaxf(ay1, by1);
    ih = fmaxf(ih, 0.0f);
    float inter = iw * ih;
    float area_a = (ax2 - ax1) * (ay2 - ay1);
    float area_b = (bx2 - bx1) * (by2 - by1);
    float uni = area_a + area_b - inter;
    return uni > 0.0f ? inter / uni : 0.0f;
}

// Async global->LDS staging of one 15360 B tile: 7 rounds x 16 B/lane + 2 x 4 B/lane
// = 120 B/lane. Zero VGPR payload (no spill risk); LDS dest is linear lane*size.
__device__ __forceinline__ void stage_tile(const float* __restrict__ g, float* s, int tid) {
#pragma unroll
    for (int j = 0; j < 7; j++) {
        __builtin_amdgcn_global_load_lds(
            (const __attribute__((address_space(1))) void*)(g + j * 512 + tid * 4),
            (__attribute__((address_space(3))) void*)(s + j * 512 + tid * 4), 16, 0, 0);
    }
#pragma unroll
    for (int j = 0; j < 2; j++) {
        __builtin_amdgcn_global_load_lds(
            (const __attribute__((address_space(1))) void*)(g + 3584 + j * 128 + tid),
            (__attribute__((address_space(3))) void*)(s + 3584 + j * 128 + tid), 4, 0, 0);
    }
}

// Per-cell loss from LDS-staged tiles (stride-30 gather, 4-way bank conflict: cheap).
__device__ __forceinline__ float cell_loss(const float* __restrict__ sd,
                                           const float* __restrict__ sl,
                                           int idx, int tid) {
    const int cell = idx % 49;
    const float r = (float)(cell / 7);
    const float c = (float)(cell % 7);

    float d[30], l[30];
    const float2* dp = (const float2*)(sd + tid * 30);
    const float2* lp = (const float2*)(sl + tid * 30);
#pragma unroll
    for (int i = 0; i < 15; i++) {
        float2 v = dp[i];
        d[2 * i] = v.x; d[2 * i + 1] = v.y;
        float2 w2 = lp[i];
        l[2 * i] = w2.x; l[2 * i + 1] = w2.y;
    }

    const float inv_g = 1.0f / 7.0f;
    float cx1 = (d[0] + c) * inv_g, cy1 = (d[1] + r) * inv_g;
    float b1x1 = cx1 - d[2] * 0.5f, b1y1 = cy1 - d[3] * 0.5f;
    float b1x2 = cx1 + d[2] * 0.5f, b1y2 = cy1 + d[3] * 0.5f;
    float cx2 = (d[5] + c) * inv_g, cy2 = (d[6] + r) * inv_g;
    float b2x1 = cx2 - d[7] * 0.5f, b2y1 = cy2 - d[8] * 0.5f;
    float b2x2 = cx2 + d[7] * 0.5f, b2y2 = cy2 + d[8] * 0.5f;
    float gx = (l[0] + c) * inv_g, gy = (l[1] + r) * inv_g;
    float gx1 = gx - l[2] * 0.5f, gy1 = gy - l[3] * 0.5f;
    float gx2 = gx + l[2] * 0.5f, gy2 = gy + l[3] * 0.5f;

    float iou1 = iou_calc(b1x1, b1y1, b1x2, b1y2, gx1, gy1, gx2, gy2);
    float iou2 = iou_calc(b2x1, b2y1, b2x2, b2y2, gx1, gy1, gx2, gy2);
    bool resp1 = iou1 >= iou2;

    float xy1 = (d[0] - l[0]) * (d[0] - l[0]) + (d[1] - l[1]) * (d[1] - l[1]);
    float xy2 = (d[5] - l[5]) * (d[5] - l[5]) + (d[6] - l[6]) * (d[6] - l[6]);
    float s2 = sqrtf(d[2]) - sqrtf(l[2]);
    float s3 = sqrtf(d[3]) - sqrtf(l[3]);
    float wh1 = s2 * s2 + s3 * s3;
    float s7 = sqrtf(d[7]) - sqrtf(l[7]);
    float s8 = sqrtf(d[8]) - sqrtf(l[8]);
    float wh2 = s7 * s7 + s8 * s8;

    float d4 = d[4], d9 = d[9];
    float co = COORD * (resp1 ? xy1 : xy2);
    float wh = COORD * (resp1 ? wh1 : wh2);
    float ci = resp1 ? (d4 - iou1) * (d4 - iou1) : (d9 - iou2) * (d9 - iou2);
    float noobj_in = NO_OBJ * (resp1 ? d9 * d9 : d4 * d4);
    float cls = 0.0f;
#pragma unroll
    for (int i = 10; i < 30; i++) {
        float t = d[i] - l[i];
        cls += t * t;
    }

    return (l[4] == 1.0f) ? (co + wh + ci + noobj_in + cls)
                          : NO_OBJ * (d4 * d4 + d9 * d9);
}

// Persistent double-buffered pipeline (unchanged from the passing r5 kernel),
// but single-launch: block partials go straight to out[0] via device-scope
// fp32 atomicAdd (out zeroed by hipMemsetAsync on the stream). 512 atomics to
// one address pipeline in the TCC and overlap the block-drain tail.
__global__ __launch_bounds__(CPB) void yolo_loss_kernel(
    const float* __restrict__ data, const float* __restrict__ labels,
    float* __restrict__ out) {
    __shared__ float sd[2][FPT];
    __shared__ float sl[2][FPT];

    const int tid = threadIdx.x;
    float acc = 0.0f;
    int cur = 0;

    // prologue: stage first tile
    stage_tile(data + (size_t)blockIdx.x * FPT, sd[0], tid);
    stage_tile(labels + (size_t)blockIdx.x * FPT, sl[0], tid);

    for (int i = blockIdx.x; i < NTILES; i += NPBLK) {
        __syncthreads();  // vmcnt drain: buf[cur] staged + all waves done with buf[cur^1]
        const int nxt = i + NPBLK;
        if (nxt < NTILES) {
            stage_tile(data + (size_t)nxt * FPT, sd[cur ^ 1], tid);
            stage_tile(labels + (size_t)nxt * FPT, sl[cur ^ 1], tid);
        }
        acc += cell_loss(sd[cur], sl[cur], i * CPB + tid, tid);
        cur ^= 1;
    }
    acc *= INV_B;

    // wave reduction -> per-block partial
#pragma unroll
    for (int off = 32; off > 0; off >>= 1)
        acc += __shfl_down(acc, off, 64);

    __syncthreads();  // all waves done with LDS buffers; reuse sd[0] for exchange
    if ((tid & 63) == 0) sd[0][tid >> 6] = acc;
    __syncthreads();
    if (tid == 0) atomicAdd(out, sd[0][0] + sd[0][1]);
}

extern "C" void kernel_launch(void* const* d_in, const int* in_sizes, int n_in,
                              void* d_out, int out_size, void* d_ws, size_t ws_size,
                              hipStream_t stream) {
    const float* data = (const float*)d_in[0];
    const float* labels = (const float*)d_in[1];
    float* out = (float*)d_out;

    hipMemsetAsync(out, 0, sizeof(float), stream);  // stream-ordered, graph-capturable
    yolo_loss_kernel<<<NPBLK, CPB, 0, stream>>>(data, labels, out);
}

// Round 7
// 111.212 us; speedup vs baseline: 1.0460x; 1.0460x over previous
//
#include <hip/hip_runtime.h>

#define COORD 5.0f
#define NO_OBJ 0.5f
#define NCELLS (8192 * 49)
#define INV_B (1.0f / 8192.0f)

#define CPB 64                       // one wave per block: no barriers needed
#define FPT (CPB * 30)               // 1920 floats (7680 B) per array per tile
#define NTILES (NCELLS / CPB)        // 6272 tiles
#define NPBLK 1280                   // 5 blocks/CU (LDS-capped), 4-5 tiles each

__device__ __forceinline__ float iou_calc(float ax1, float ay1, float ax2, float ay2,
                                          float bx1, float by1, float bx2, float by2) {
    float iw = fminf(ax2, bx2) - fmaxf(ax1, bx1);
    iw = fmaxf(iw, 0.0f);
    float ih = fminf(ay2, by2) - fmaxf(ay1, by1);
    ih = fmaxf(ih, 0.0f);
    float inter = iw * ih;
    float area_a = (ax2 - ax1) * (ay2 - ay1);
    float area_b = (bx2 - bx1) * (by2 - by1);
    float uni = area_a + area_b - inter;
    return uni > 0.0f ? inter / uni : 0.0f;
}

// Async global->LDS staging of one 7680 B array-tile: 7 x 16 B/lane + 2 x 4 B/lane
// = 9 vmcnt events per call (18 per tile incl. labels). Zero VGPR payload; LDS
// dest is linear lane*size (gload_lds constraint).
__device__ __forceinline__ void stage_tile(const float* __restrict__ g, float* s, int tid) {
#pragma unroll
    for (int j = 0; j < 7; j++) {
        __builtin_amdgcn_global_load_lds(
            (const __attribute__((address_space(1))) void*)(g + j * 256 + tid * 4),
            (__attribute__((address_space(3))) void*)(s + j * 256 + tid * 4), 16, 0, 0);
    }
#pragma unroll
    for (int j = 0; j < 2; j++) {
        __builtin_amdgcn_global_load_lds(
            (const __attribute__((address_space(1))) void*)(g + 1792 + j * 64 + tid),
            (__attribute__((address_space(3))) void*)(s + 1792 + j * 64 + tid), 4, 0, 0);
    }
}

// Per-cell loss from LDS-staged tiles (stride-30 gather, 4-way bank conflict: cheap).
__device__ __forceinline__ float cell_loss(const float* __restrict__ sd,
                                           const float* __restrict__ sl,
                                           int idx, int tid) {
    const int cell = idx % 49;
    const float r = (float)(cell / 7);
    const float c = (float)(cell % 7);

    float d[30], l[30];
    const float2* dp = (const float2*)(sd + tid * 30);
    const float2* lp = (const float2*)(sl + tid * 30);
#pragma unroll
    for (int i = 0; i < 15; i++) {
        float2 v = dp[i];
        d[2 * i] = v.x; d[2 * i + 1] = v.y;
        float2 w2 = lp[i];
        l[2 * i] = w2.x; l[2 * i + 1] = w2.y;
    }

    const float inv_g = 1.0f / 7.0f;
    float cx1 = (d[0] + c) * inv_g, cy1 = (d[1] + r) * inv_g;
    float b1x1 = cx1 - d[2] * 0.5f, b1y1 = cy1 - d[3] * 0.5f;
    float b1x2 = cx1 + d[2] * 0.5f, b1y2 = cy1 + d[3] * 0.5f;
    float cx2 = (d[5] + c) * inv_g, cy2 = (d[6] + r) * inv_g;
    float b2x1 = cx2 - d[7] * 0.5f, b2y1 = cy2 - d[8] * 0.5f;
    float b2x2 = cx2 + d[7] * 0.5f, b2y2 = cy2 + d[8] * 0.5f;
    float gx = (l[0] + c) * inv_g, gy = (l[1] + r) * inv_g;
    float gx1 = gx - l[2] * 0.5f, gy1 = gy - l[3] * 0.5f;
    float gx2 = gx + l[2] * 0.5f, gy2 = gy + l[3] * 0.5f;

    float iou1 = iou_calc(b1x1, b1y1, b1x2, b1y2, gx1, gy1, gx2, gy2);
    float iou2 = iou_calc(b2x1, b2y1, b2x2, b2y2, gx1, gy1, gx2, gy2);
    bool resp1 = iou1 >= iou2;

    float xy1 = (d[0] - l[0]) * (d[0] - l[0]) + (d[1] - l[1]) * (d[1] - l[1]);
    float xy2 = (d[5] - l[5]) * (d[5] - l[5]) + (d[6] - l[6]) * (d[6] - l[6]);
    float s2 = sqrtf(d[2]) - sqrtf(l[2]);
    float s3 = sqrtf(d[3]) - sqrtf(l[3]);
    float wh1 = s2 * s2 + s3 * s3;
    float s7 = sqrtf(d[7]) - sqrtf(l[7]);
    float s8 = sqrtf(d[8]) - sqrtf(l[8]);
    float wh2 = s7 * s7 + s8 * s8;

    float d4 = d[4], d9 = d[9];
    float co = COORD * (resp1 ? xy1 : xy2);
    float wh = COORD * (resp1 ? wh1 : wh2);
    float ci = resp1 ? (d4 - iou1) * (d4 - iou1) : (d9 - iou2) * (d9 - iou2);
    float noobj_in = NO_OBJ * (resp1 ? d9 * d9 : d4 * d4);
    float cls = 0.0f;
#pragma unroll
    for (int i = 10; i < 30; i++) {
        float t = d[i] - l[i];
        cls += t * t;
    }

    return (l[4] == 1.0f) ? (co + wh + ci + noobj_in + cls)
                          : NO_OBJ * (d4 * d4 + d9 * d9);
}

// Single-wave persistent blocks, 2-deep counted-vmcnt pipeline (T3/T4 pattern):
// the wave NEVER drains vmcnt to 0 in the steady loop — s_waitcnt vmcnt(18)
// waits only the older tile's 18 gload_lds while the newer tile's 18 stay in
// flight. No __syncthreads anywhere in the loop (single wave), so the compiler
// never inserts a full vmcnt(0) drain. 5 blocks/CU keep 75-150 KB/CU of reads
// outstanding continuously.
__global__ __launch_bounds__(CPB) void yolo_loss_kernel(
    const float* __restrict__ data, const float* __restrict__ labels,
    float* __restrict__ ws) {
    __shared__ float sd[2][FPT];
    __shared__ float sl[2][FPT];

    const int tid = threadIdx.x;
    const int bid = blockIdx.x;
    const int n = (NTILES - bid + NPBLK - 1) / NPBLK;  // 4 or 5 tiles

    // prologue: stage tiles 0 and 1 (36 loads in flight)
    stage_tile(data + (size_t)bid * FPT, sd[0], tid);
    stage_tile(labels + (size_t)bid * FPT, sl[0], tid);
    if (n > 1) {
        const size_t t1 = (size_t)(bid + NPBLK) * FPT;
        stage_tile(data + t1, sd[1], tid);
        stage_tile(labels + t1, sl[1], tid);
    }

    float acc = 0.0f;
    for (int i = 0; i < n; ++i) {
        const int cur = i & 1;
        // wait for the OLDER tile's 18 loads only (counted, not a drain)...
        if (i + 1 < n) {
            asm volatile("s_waitcnt vmcnt(18)" ::: "memory");
        } else {
            asm volatile("s_waitcnt vmcnt(0)" ::: "memory");  // tail only
        }
        acc += cell_loss(sd[cur], sl[cur], (bid + i * NPBLK) * CPB + tid, tid);
        if (i + 2 < n) {
            // ds_reads of buf[cur] are consumed (compiler-waited); fence anyway so
            // the refill can't be hoisted above the reads, then reuse the buffer.
            asm volatile("s_waitcnt lgkmcnt(0)" ::: "memory");
            const size_t t2 = (size_t)(bid + (i + 2) * NPBLK) * FPT;
            stage_tile(data + t2, sd[cur], tid);
            stage_tile(labels + t2, sl[cur], tid);
        }
    }
    acc *= INV_B;

    // single-wave shuffle reduction -> per-block partial
#pragma unroll
    for (int off = 32; off > 0; off >>= 1)
        acc += __shfl_down(acc, off, 64);
    if (tid == 0) ws[bid] = acc;
}

__global__ __launch_bounds__(256) void reduce_kernel(const float* __restrict__ ws,
                                                     float* __restrict__ out) {
    float s = 0.0f;
    for (int i = threadIdx.x; i < NPBLK; i += 256) s += ws[i];
#pragma unroll
    for (int off = 32; off > 0; off >>= 1)
        s += __shfl_down(s, off, 64);
    __shared__ float w[4];
    if ((threadIdx.x & 63) == 0) w[threadIdx.x >> 6] = s;
    __syncthreads();
    if (threadIdx.x == 0) out[0] = w[0] + w[1] + w[2] + w[3];
}

extern "C" void kernel_launch(void* const* d_in, const int* in_sizes, int n_in,
                              void* d_out, int out_size, void* d_ws, size_t ws_size,
                              hipStream_t stream) {
    const float* data = (const float*)d_in[0];
    const float* labels = (const float*)d_in[1];
    float* out = (float*)d_out;
    float* ws = (float*)d_ws;  // NPBLK floats of scratch

    yolo_loss_kernel<<<NPBLK, CPB, 0, stream>>>(data, labels, ws);
    reduce_kernel<<<1, 256, 0, stream>>>(ws, out);
}